// Round 1
// baseline (7695.268 us; speedup 1.0000x reference)
//
#include <hip/hip_runtime.h>
#include <math.h>

#define B 32
#define T 50
#define H 1024
#define E 128
#define V 32000
#define G4 4096   // 4*H
#define HE 1152   // H+E

__device__ __forceinline__ float sigm(float x){ return 1.0f/(1.0f+expf(-x)); }

// encp[b][e] = proj_b[e] + sum_j enc[b][j] * proj_w[e][E+j]
__global__ void k_encp(const float* __restrict__ enc, const float* __restrict__ pw,
                       const float* __restrict__ pb, float* __restrict__ encp){
  int b = blockIdx.x, e = threadIdx.x;
  const float* er = enc + b*H;
  const float* wr = pw + e*HE + E;
  float acc = pb[e];
  for (int j=0;j<H;j+=4){
    float4 w4 = *(const float4*)(wr+j);
    float4 e4 = *(const float4*)(er+j);
    acc += w4.x*e4.x + w4.y*e4.y + w4.z*e4.z + w4.w*e4.w;
  }
  encp[b*E+e] = acc;
}

// P[t][e][b] = encp[b][e] + sum_j target[b][t][j] * proj_w[e][j]
__global__ void k_proj(const float* __restrict__ target, const float* __restrict__ pw,
                       const float* __restrict__ encp, float* __restrict__ P){
  int t = blockIdx.x / B, b = blockIdx.x % B, e = threadIdx.x;
  const float* xr = target + (b*T + t)*E;
  const float* wr = pw + e*HE;
  float acc = encp[b*E+e];
  for (int j=0;j<E;j+=4){
    float4 w4 = *(const float4*)(wr+j);
    float4 x4 = *(const float4*)(xr+j);
    acc += w4.x*x4.x + w4.y*x4.y + w4.z*x4.z + w4.w*x4.w;
  }
  P[(t*E + e)*B + b] = acc;
}

// xg0[t][r][b] = b_ih0[r]+b_hh0[r] + sum_e w_ih0[r][e] * P[t][e][b]
__global__ void k_xg0(const float* __restrict__ wih0, const float* __restrict__ bih0,
                      const float* __restrict__ bhh0, const float* __restrict__ P,
                      float* __restrict__ xg){
  int idx = blockIdx.x*256 + threadIdx.x;   // t*G4*B + r*B + b, total 6,553,600
  int b = idx & 31; int r = (idx >> 5) & 4095; int t = idx >> 17;
  const float* wr = wih0 + r*E;
  const float* pr = P + t*E*B + b;
  float acc = bih0[r] + bhh0[r];
  #pragma unroll 8
  for (int e=0;e<E;e++) acc += wr[e] * pr[e*B];
  xg[idx] = acc;
}

// state layout: s[h*B + b]
__global__ void k_init(const float* __restrict__ enc, float* __restrict__ h0, float* __restrict__ c0,
                       float* __restrict__ h1, float* __restrict__ c1){
  int idx = blockIdx.x*256 + threadIdx.x;   // 32768
  int b = idx & 31, h = idx >> 5;
  float v = enc[b*H + h];
  h0[idx]=v; c0[idx]=v; h1[idx]=v; c1[idx]=v;
}

// layer0 cell: wave per h; lane = b + 32*kh
__global__ __launch_bounds__(256) void k_cell0(const float* __restrict__ whh, const float* __restrict__ xg_t,
                       const float* __restrict__ h_in, float* __restrict__ h_out,
                       float* __restrict__ c){
  int h = (blockIdx.x*256 + threadIdx.x) >> 6;    // 0..1023
  int lane = threadIdx.x & 63;
  int b = lane & 31, kh = lane >> 5;
  const float* w0 = whh + (0*H + h)*H + kh*512;
  const float* w1 = whh + (1*H + h)*H + kh*512;
  const float* w2 = whh + (2*H + h)*H + kh*512;
  const float* w3 = whh + (3*H + h)*H + kh*512;
  const float* hk = h_in + (kh*512)*B + b;
  float a0=0,a1=0,a2=0,a3=0, p0=0,p1=0,p2=0,p3=0;
  #pragma unroll 4
  for (int k=0;k<512;k+=4){
    float4 w40 = *(const float4*)(w0+k);
    float4 w41 = *(const float4*)(w1+k);
    float4 w42 = *(const float4*)(w2+k);
    float4 w43 = *(const float4*)(w3+k);
    float hv0 = hk[(k+0)*B], hv1 = hk[(k+1)*B], hv2 = hk[(k+2)*B], hv3 = hk[(k+3)*B];
    a0 += w40.x*hv0 + w40.y*hv1;  p0 += w40.z*hv2 + w40.w*hv3;
    a1 += w41.x*hv0 + w41.y*hv1;  p1 += w41.z*hv2 + w41.w*hv3;
    a2 += w42.x*hv0 + w42.y*hv1;  p2 += w42.z*hv2 + w42.w*hv3;
    a3 += w43.x*hv0 + w43.y*hv1;  p3 += w43.z*hv2 + w43.w*hv3;
  }
  float g0=a0+p0, g1=a1+p1, g2=a2+p2, g3=a3+p3;
  g0 += __shfl_xor(g0, 32);
  g1 += __shfl_xor(g1, 32);
  g2 += __shfl_xor(g2, 32);
  g3 += __shfl_xor(g3, 32);
  g0 += xg_t[(0*H+h)*B + b];
  g1 += xg_t[(1*H+h)*B + b];
  g2 += xg_t[(2*H+h)*B + b];
  g3 += xg_t[(3*H+h)*B + b];
  float ig = sigm(g0), fg = sigm(g1), gg = tanhf(g2), og = sigm(g3);
  int sidx = h*B + b;
  float cn = fg*c[sidx] + ig*gg;
  float hn = og*tanhf(cn);
  if (kh==0){ c[sidx]=cn; h_out[sidx]=hn; }
}

// layer1 cell: gates = h0n @ wih.T + h_in @ whh.T + biases
__global__ __launch_bounds__(256) void k_cell1(const float* __restrict__ wih, const float* __restrict__ whh,
                       const float* __restrict__ bih, const float* __restrict__ bhh,
                       const float* __restrict__ h0n, const float* __restrict__ h_in,
                       float* __restrict__ h_out, float* __restrict__ c,
                       float* __restrict__ H1t){
  int h = (blockIdx.x*256 + threadIdx.x) >> 6;
  int lane = threadIdx.x & 63;
  int b = lane & 31, kh = lane >> 5;
  float a0=0,a1=0,a2=0,a3=0, p0=0,p1=0,p2=0,p3=0;
  {
    const float* w0 = wih + (0*H + h)*H + kh*512;
    const float* w1 = wih + (1*H + h)*H + kh*512;
    const float* w2 = wih + (2*H + h)*H + kh*512;
    const float* w3 = wih + (3*H + h)*H + kh*512;
    const float* hk = h0n + (kh*512)*B + b;
    #pragma unroll 4
    for (int k=0;k<512;k+=4){
      float4 w40 = *(const float4*)(w0+k);
      float4 w41 = *(const float4*)(w1+k);
      float4 w42 = *(const float4*)(w2+k);
      float4 w43 = *(const float4*)(w3+k);
      float hv0 = hk[(k+0)*B], hv1 = hk[(k+1)*B], hv2 = hk[(k+2)*B], hv3 = hk[(k+3)*B];
      a0 += w40.x*hv0 + w40.y*hv1;  p0 += w40.z*hv2 + w40.w*hv3;
      a1 += w41.x*hv0 + w41.y*hv1;  p1 += w41.z*hv2 + w41.w*hv3;
      a2 += w42.x*hv0 + w42.y*hv1;  p2 += w42.z*hv2 + w42.w*hv3;
      a3 += w43.x*hv0 + w43.y*hv1;  p3 += w43.z*hv2 + w43.w*hv3;
    }
  }
  {
    const float* w0 = whh + (0*H + h)*H + kh*512;
    const float* w1 = whh + (1*H + h)*H + kh*512;
    const float* w2 = whh + (2*H + h)*H + kh*512;
    const float* w3 = whh + (3*H + h)*H + kh*512;
    const float* hk = h_in + (kh*512)*B + b;
    #pragma unroll 4
    for (int k=0;k<512;k+=4){
      float4 w40 = *(const float4*)(w0+k);
      float4 w41 = *(const float4*)(w1+k);
      float4 w42 = *(const float4*)(w2+k);
      float4 w43 = *(const float4*)(w3+k);
      float hv0 = hk[(k+0)*B], hv1 = hk[(k+1)*B], hv2 = hk[(k+2)*B], hv3 = hk[(k+3)*B];
      a0 += w40.x*hv0 + w40.y*hv1;  p0 += w40.z*hv2 + w40.w*hv3;
      a1 += w41.x*hv0 + w41.y*hv1;  p1 += w41.z*hv2 + w41.w*hv3;
      a2 += w42.x*hv0 + w42.y*hv1;  p2 += w42.z*hv2 + w42.w*hv3;
      a3 += w43.x*hv0 + w43.y*hv1;  p3 += w43.z*hv2 + w43.w*hv3;
    }
  }
  float g0=a0+p0, g1=a1+p1, g2=a2+p2, g3=a3+p3;
  g0 += __shfl_xor(g0, 32);
  g1 += __shfl_xor(g1, 32);
  g2 += __shfl_xor(g2, 32);
  g3 += __shfl_xor(g3, 32);
  g0 += bih[0*H+h] + bhh[0*H+h];
  g1 += bih[1*H+h] + bhh[1*H+h];
  g2 += bih[2*H+h] + bhh[2*H+h];
  g3 += bih[3*H+h] + bhh[3*H+h];
  float ig = sigm(g0), fg = sigm(g1), gg = tanhf(g2), og = sigm(g3);
  int sidx = h*B + b;
  float cn = fg*c[sidx] + ig*gg;
  float hn = og*tanhf(cn);
  if (kh==0){ c[sidx]=cn; h_out[sidx]=hn; H1t[sidx]=hn; }
}

// C[row(b,t)][n] = sum_k H1[t][k][b] * lin_w[n][k] + lin_b[n]
#define BM 128
#define BN 64
#define BK 32
__global__ __launch_bounds__(256) void k_gemm(const float* __restrict__ H1, const float* __restrict__ lw,
                      const float* __restrict__ lb, float* __restrict__ out){
  __shared__ float As[BK][BM];
  __shared__ float Ws[BN][BK+1];
  int tid = threadIdx.x;
  int bm = blockIdx.x % 13;
  int bn = blockIdx.x / 13;
  int m0 = bm*BM, n0 = bn*BN;
  int tx = tid & 15, ty = tid >> 4;
  float acc[8][4] = {};
  for (int k0=0;k0<H;k0+=BK){
    #pragma unroll
    for (int i=0;i<16;i++){
      int idx = tid + i*256;
      int m_l = idx & 127, k_l = idx >> 7;
      int m = m0 + m_l;
      float v = 0.f;
      if (m < B*T){
        int t = m >> 5, b = m & 31;
        v = H1[(t*H + k0 + k_l)*B + b];
      }
      As[k_l][m_l] = v;
    }
    #pragma unroll
    for (int i=0;i<2;i++){
      int idx = tid + i*256;
      int n_l = idx >> 3, k4 = (idx & 7)*4;
      float4 w4 = *(const float4*)(lw + (n0+n_l)*H + k0 + k4);
      Ws[n_l][k4]=w4.x; Ws[n_l][k4+1]=w4.y; Ws[n_l][k4+2]=w4.z; Ws[n_l][k4+3]=w4.w;
    }
    __syncthreads();
    #pragma unroll
    for (int k=0;k<BK;k++){
      float a[8], w[4];
      #pragma unroll
      for (int i=0;i<8;i++) a[i] = As[k][ty*8+i];
      #pragma unroll
      for (int j=0;j<4;j++) w[j] = Ws[tx*4+j][k];
      #pragma unroll
      for (int i=0;i<8;i++)
        #pragma unroll
        for (int j=0;j<4;j++)
          acc[i][j] += a[i]*w[j];
    }
    __syncthreads();
  }
  float bias[4];
  #pragma unroll
  for (int j=0;j<4;j++) bias[j] = lb[n0 + tx*4 + j];
  #pragma unroll
  for (int i=0;i<8;i++){
    int m = m0 + ty*8 + i;
    if (m < B*T){
      int t = m>>5, b = m&31;
      long row = (long)(b*T + t)*V + n0 + tx*4;
      #pragma unroll
      for (int j=0;j<4;j++) out[row + j] = acc[i][j] + bias[j];
    }
  }
}

__global__ __launch_bounds__(256) void k_lsm(float* __restrict__ out){
  __shared__ float red[256];
  float* row = out + (long)blockIdx.x * V;
  int tid = threadIdx.x;
  float m = -INFINITY;
  for (int n=tid;n<V;n+=256) m = fmaxf(m, row[n]);
  red[tid]=m; __syncthreads();
  for (int s=128;s>0;s>>=1){ if(tid<s) red[tid]=fmaxf(red[tid],red[tid+s]); __syncthreads(); }
  m = red[0]; __syncthreads();
  float s = 0.f;
  for (int n=tid;n<V;n+=256) s += expf(row[n]-m);
  red[tid]=s; __syncthreads();
  for (int st=128;st>0;st>>=1){ if(tid<st) red[tid]+=red[tid+st]; __syncthreads(); }
  s = red[0];
  float lse = m + logf(s);
  for (int n=tid;n<V;n+=256) row[n] = row[n]-lse;
}

extern "C" void kernel_launch(void* const* d_in, const int* in_sizes, int n_in,
                              void* d_out, int out_size, void* d_ws, size_t ws_size,
                              hipStream_t stream){
  const float* enc    = (const float*)d_in[0];
  const float* target = (const float*)d_in[1];
  const float* pw     = (const float*)d_in[2];
  const float* pb     = (const float*)d_in[3];
  const float* wih0   = (const float*)d_in[4];
  const float* whh0   = (const float*)d_in[5];
  const float* bih0   = (const float*)d_in[6];
  const float* bhh0   = (const float*)d_in[7];
  const float* wih1   = (const float*)d_in[8];
  const float* whh1   = (const float*)d_in[9];
  const float* bih1   = (const float*)d_in[10];
  const float* bhh1   = (const float*)d_in[11];
  const float* lw     = (const float*)d_in[12];
  const float* lb     = (const float*)d_in[13];
  float* out = (float*)d_out;

  float* ws   = (float*)d_ws;
  float* xg0  = ws;                       // T*G4*B   = 6,553,600 f
  float* P    = xg0 + (long)T*G4*B;       // T*E*B    = 204,800 f
  float* encp = P + T*E*B;                // B*E      = 4,096 f
  float* h0a  = encp + B*E;
  float* h0b  = h0a + H*B;
  float* c0   = h0b + H*B;
  float* h1a  = c0 + H*B;
  float* h1b  = h1a + H*B;
  float* c1   = h1b + H*B;
  float* H1   = c1 + H*B;                 // T*H*B    = 1,638,400 f

  k_encp<<<B, E, 0, stream>>>(enc, pw, pb, encp);
  k_proj<<<T*B, E, 0, stream>>>(target, pw, encp, P);
  k_xg0<<<(T*G4*B)/256, 256, 0, stream>>>(wih0, bih0, bhh0, P, xg0);
  k_init<<<(H*B)/256, 256, 0, stream>>>(enc, h0a, c0, h1a, c1);

  float* h0in=h0a; float* h0out=h0b;
  float* h1in=h1a; float* h1out=h1b;
  for (int t=0;t<T;t++){
    k_cell0<<<256, 256, 0, stream>>>(whh0, xg0 + (long)t*G4*B, h0in, h0out, c0);
    k_cell1<<<256, 256, 0, stream>>>(wih1, whh1, bih1, bhh1, h0out, h1in, h1out, c1,
                                     H1 + (long)t*H*B);
    float* tmp;
    tmp=h0in; h0in=h0out; h0out=tmp;
    tmp=h1in; h1in=h1out; h1out=tmp;
  }

  k_gemm<<<13*500, 256, 0, stream>>>(H1, lw, lb, out);
  k_lsm<<<B*T, 256, 0, stream>>>(out);
}